// Round 3
// baseline (386.638 us; speedup 1.0000x reference)
//
#include <hip/hip_runtime.h>
#include <math.h>

// NoisyTopkRouter: B=8,T=4096,NE=1024,E=16,TOPK=2,LIN=1824
// tokens = 32768; streamed features = 1792 (city-32 folded into a constant)
// out = [router 32768*16][indices 32768*2][gate1 32768*16] all f32
//
// R3: lane = token (64 tok/block, grid 512, 2 blocks/CU). Waves split each
// 64-k chunk into 16-k quarters (split-K, LDS-reduced). A staged in LDS
// (pad 68 -> conflict-free lane-strided b128). W is wave-uniform: addresses
// built from readfirstlane(w) so the backend emits scalar s_load; v_fmac
// reads W from SGPR. LDS traffic: 4 b128 per 512 FMAs (was 32 per 256).

#define TOKS 64
#define NCHUNK 28
#define I_OFF 524288        // 32768*16
#define G_OFF 589824        // 524288 + 32768*2
#define SA_STRIDE 68        // pad 64->68: lane-strided b128 sweeps all banks
#define SS_STRIDE 132

__device__ __forceinline__ float softplus_f(float x) {
  // jax.nn.softplus = max(x,0) + log1p(exp(-|x|))
  return fmaxf(x, 0.0f) + log1pf(expf(-fabsf(x)));
}

__device__ __forceinline__ float get_comp(const float4& v, int kk) {
  return kk == 0 ? v.x : kk == 1 ? v.y : kk == 2 ? v.z : v.w;
}

__global__ __launch_bounds__(256, 2) void router_kernel(
    const float* __restrict__ mh, const float* __restrict__ dt,
    const float* __restrict__ dd, const float* __restrict__ rg,
    const float* __restrict__ de, const float* __restrict__ cemb_all,
    const float* __restrict__ w_route, const float* __restrict__ b_route,
    const float* __restrict__ w_noise, const float* __restrict__ b_noise,
    const float* __restrict__ eps, const int* __restrict__ city_index,
    float* __restrict__ out) {
  // union: A tile [64][68] (4352 f) vs scores [64][132] (8448 f)
  __shared__ float smem[8448];
  __shared__ float city_l[32];
  float* sA = smem;
  float* sS = smem;

  const int tid = threadIdx.x;
  const int ln  = tid & 63;                               // lane = token
  const int w   = tid >> 6;                               // k-quarter
  const int wu  = __builtin_amdgcn_readfirstlane(w);      // uniform wave id
  const int blockTok = blockIdx.x * TOKS;

  // ---- constant: bias + city_embed . W[1024:1056] ----
  if (tid < 32) {
    const int e = tid & 15;
    const float* wsrc = (tid < 16) ? w_route : w_noise;
    const float* bsrc = (tid < 16) ? b_route : b_noise;
    const float* ce = cemb_all + city_index[0] * 32;
    float s = bsrc[e];
#pragma unroll
    for (int j = 0; j < 32; ++j) s = fmaf(ce[j], wsrc[(1024 + j) * 16 + e], s);
    city_l[tid] = s;
  }

  float acc[32];
#pragma unroll
  for (int e = 0; e < 32; ++e) acc[e] = 0.0f;

  // A staging coords: 64 rows x 16 float4; thread: col4 = tid&15, rows tid>>4 (+16*s)
  const int acol = (tid & 15) * 4;
  const int arow = tid >> 4;

  float4 AR0, AR1, AR2, AR3;  // named regs: no spill

  auto a_src = [&](int g, int row) -> const float* {
    const float* base; int stride;
    if (g < 16)      { base = mh + g * 64;        stride = 1024; }
    else if (g < 20) { base = dt + (g - 16) * 64; stride = 256; }
    else if (g < 24) { base = dd + (g - 20) * 64; stride = 256; }
    else if (g < 26) { base = rg + (g - 24) * 64; stride = 128; }
    else             { base = de + (g - 26) * 64; stride = 128; }
    return base + (size_t)(blockTok + row) * stride;
  };

  auto prefetch = [&](int g) {
    AR0 = *(const float4*)(a_src(g, arow +  0) + acol);
    AR1 = *(const float4*)(a_src(g, arow + 16) + acol);
    AR2 = *(const float4*)(a_src(g, arow + 32) + acol);
    AR3 = *(const float4*)(a_src(g, arow + 48) + acol);
  };

  prefetch(0);

  for (int c = 0; c < NCHUNK; ++c) {
    __syncthreads();  // previous compute done -> A buffer free
    *(float4*)&sA[(arow +  0) * SA_STRIDE + acol] = AR0;
    *(float4*)&sA[(arow + 16) * SA_STRIDE + acol] = AR1;
    *(float4*)&sA[(arow + 32) * SA_STRIDE + acol] = AR2;
    *(float4*)&sA[(arow + 48) * SA_STRIDE + acol] = AR3;
    __syncthreads();  // tile visible

    if (c + 1 < NCHUNK) prefetch(c + 1);  // global loads in flight over compute

    // weight row base for this wave's k-quarter (skip city rows 1024..1055)
    const int kb = c * 64 + wu * 16 + ((c >= 16) ? 32 : 0);

#pragma unroll
    for (int q = 0; q < 4; ++q) {
      // lane's token, 4 k-values: stride-68 lane pattern, conflict-free
      float4 a = *(const float4*)&sA[ln * SA_STRIDE + wu * 16 + q * 4];
#pragma unroll
      for (int kk = 0; kk < 4; ++kk) {
        const int krow = kb + q * 4 + kk;                 // uniform
        const float* Wr = w_route + krow * 16;            // uniform -> s_load
        const float* Wn = w_noise + krow * 16;            // uniform -> s_load
        const float av = get_comp(a, kk);
#pragma unroll
        for (int e = 0; e < 16; ++e) acc[e]      = fmaf(av, Wr[e], acc[e]);
#pragma unroll
        for (int e = 0; e < 16; ++e) acc[16 + e] = fmaf(av, Wn[e], acc[16 + e]);
      }
    }
  }

  // ---- split-K reduction through LDS ----
  __syncthreads();  // all waves done with sA; smem becomes scores[64][132]
#pragma unroll
  for (int e4 = 0; e4 < 8; ++e4)
    *(float4*)&sS[ln * SS_STRIDE + w * 32 + e4 * 4] =
        make_float4(acc[e4 * 4], acc[e4 * 4 + 1], acc[e4 * 4 + 2], acc[e4 * 4 + 3]);
  __syncthreads();

  // ---- epilogue: one lane per token ----
  if (tid < TOKS) {
    const int tokg = blockTok + tid;
    float l[32];
#pragma unroll
    for (int e4 = 0; e4 < 8; ++e4) {
      float4 s0 = *(const float4*)&sS[tid * SS_STRIDE +  0 + e4 * 4];
      float4 s1 = *(const float4*)&sS[tid * SS_STRIDE + 32 + e4 * 4];
      float4 s2 = *(const float4*)&sS[tid * SS_STRIDE + 64 + e4 * 4];
      float4 s3 = *(const float4*)&sS[tid * SS_STRIDE + 96 + e4 * 4];
      l[e4 * 4 + 0] = s0.x + s1.x + s2.x + s3.x + city_l[e4 * 4 + 0];
      l[e4 * 4 + 1] = s0.y + s1.y + s2.y + s3.y + city_l[e4 * 4 + 1];
      l[e4 * 4 + 2] = s0.z + s1.z + s2.z + s3.z + city_l[e4 * 4 + 2];
      l[e4 * 4 + 3] = s0.w + s1.w + s2.w + s3.w + city_l[e4 * 4 + 3];
    }

    const float* ep = eps + (size_t)tokg * 16;
    float n[16];
#pragma unroll
    for (int e = 0; e < 16; ++e)
      n[e] = fmaf(ep[e], softplus_f(l[16 + e]), l[e]);

    // top-2, lowest-index tie-break (matches lax.top_k)
    float m1 = -INFINITY; int i1 = 0;
#pragma unroll
    for (int e = 0; e < 16; ++e)
      if (n[e] > m1) { m1 = n[e]; i1 = e; }
    float m2 = -INFINITY; int i2 = 0;
#pragma unroll
    for (int e = 0; e < 16; ++e)
      if (e != i1 && n[e] > m2) { m2 = n[e]; i2 = e; }

    float ex[16], Z = 0.f;
#pragma unroll
    for (int e = 0; e < 16; ++e) { ex[e] = expf(n[e] - m1); Z += ex[e]; }
    const float invZ  = 1.0f / Z;
    const float invZ2 = 1.0f / (1.0f + expf(m2 - m1));  // ex[i1]=1

    float r[16], g1[16];
#pragma unroll
    for (int e = 0; e < 16; ++e) {
      r[e]  = (e == i1 || e == i2) ? ex[e] * invZ2 : 0.0f;
      g1[e] = ex[e] * invZ;
    }

    float* ro = out + (size_t)tokg * 16;
#pragma unroll
    for (int e4 = 0; e4 < 4; ++e4)
      *(float4*)(ro + e4 * 4) = make_float4(r[e4*4], r[e4*4+1], r[e4*4+2], r[e4*4+3]);

    out[I_OFF + (size_t)tokg * 2 + 0] = (float)i1;
    out[I_OFF + (size_t)tokg * 2 + 1] = (float)i2;

    float* go = out + G_OFF + (size_t)tokg * 16;
#pragma unroll
    for (int e4 = 0; e4 < 4; ++e4)
      *(float4*)(go + e4 * 4) = make_float4(g1[e4*4], g1[e4*4+1], g1[e4*4+2], g1[e4*4+3]);
  }
}

extern "C" void kernel_launch(void* const* d_in, const int* in_sizes, int n_in,
                              void* d_out, int out_size, void* d_ws, size_t ws_size,
                              hipStream_t stream) {
  const float* mh = (const float*)d_in[0];   // [8,4096,1024]
  const float* dt = (const float*)d_in[1];   // [8,4096,256]
  const float* dd = (const float*)d_in[2];   // [8,4096,256]
  const float* rg = (const float*)d_in[3];   // [8,4096,128]
  const float* de = (const float*)d_in[4];   // [8,4096,128]
  const float* ce = (const float*)d_in[5];   // [4,32]
  const float* wr = (const float*)d_in[6];   // [1824,16]
  const float* br = (const float*)d_in[7];   // [16]
  const float* wn = (const float*)d_in[8];   // [1824,16]
  const float* bn = (const float*)d_in[9];   // [16]
  const float* ep = (const float*)d_in[10];  // [8,4096,16]
  const int*   ci = (const int*)d_in[11];    // scalar
  float* out = (float*)d_out;

  router_kernel<<<512, 256, 0, stream>>>(mh, dt, dd, rg, de, ce, wr, br, wn, bn,
                                         ep, ci, out);
}

// Round 4
// 297.046 us; speedup vs baseline: 1.3016x; 1.3016x over previous
//
#include <hip/hip_runtime.h>
#include <math.h>

// NoisyTopkRouter: B=8,T=4096,NE=1024,E=16,TOPK=2,LIN=1824
// tokens = 32768; streamed features = 1792 (city-32 folded into a constant)
// out = [router 32768*16][indices 32768*2][gate1 32768*16] all f32
//
// R4: LDS-issue-bound fix. Lane tile 8 tok x 8 e -> 16 FMA per ds_read_b128
// (R2 was 4). 512 thr/block, 128 tok/block, grid 256 (1 block/CU); 8 waves
// each own an 8-k slab per 64-k chunk (8-way split-K, serial-RMW reduced).
// A dbuf [2][128][68] + W dbuf [2][64][36] in LDS; one barrier per chunk.

#define TOKS 128
#define NCHUNK 28
#define I_OFF 524288        // 32768*16
#define G_OFF 589824        // 524288 + 32768*2
#define SA 68               // pad 64->68: bank stride 4 -> 2-way (free, m136)
#define SW 36               // pad 32->36: conflict-free
#define SS 36               // score rows

__device__ __forceinline__ float softplus_f(float x) {
  // jax.nn.softplus = max(x,0) + log1p(exp(-|x|))
  return fmaxf(x, 0.0f) + log1pf(expf(-fabsf(x)));
}

__device__ __forceinline__ float get_comp(const float4& v, int kk) {
  return kk == 0 ? v.x : kk == 1 ? v.y : kk == 2 ? v.z : v.w;
}

__global__ __launch_bounds__(512, 2) void router_kernel(
    const float* __restrict__ mh, const float* __restrict__ dt,
    const float* __restrict__ dd, const float* __restrict__ rg,
    const float* __restrict__ de, const float* __restrict__ cemb_all,
    const float* __restrict__ w_route, const float* __restrict__ b_route,
    const float* __restrict__ w_noise, const float* __restrict__ b_noise,
    const float* __restrict__ eps, const int* __restrict__ city_index,
    float* __restrict__ out) {
  // A dbuf 2*128*68=17408 f | W dbuf 2*64*36=4608 f ; scores [128][36] overlay A0
  __shared__ float smem[22016];
  __shared__ float city_l[32];
  float* sA0 = smem;
  float* sA1 = smem + 8704;
  float* sW0 = smem + 17408;
  float* sW1 = smem + 19712;
  float* sS  = smem;  // after final barrier

  const int tid = threadIdx.x;
  const int w   = tid >> 6;        // wave 0..7: k-slab [w*8, w*8+8) of each chunk
  const int ln  = tid & 63;
  const int tg  = ln & 15;         // tokens {tg + 16j}, j=0..7
  const int eg  = ln >> 4;         // e-cols eg*8..eg*8+7 (of 32 = route|noise)
  const int blockTok = blockIdx.x * TOKS;

  // ---- constant: bias + city_embed . W[1024:1056] ----
  if (tid < 32) {
    const int e = tid & 15;
    const float* wsrc = (tid < 16) ? w_route : w_noise;
    const float* bsrc = (tid < 16) ? b_route : b_noise;
    const float* ce = cemb_all + city_index[0] * 32;
    float s = bsrc[e];
#pragma unroll
    for (int j = 0; j < 32; ++j) s = fmaf(ce[j], wsrc[(1024 + j) * 16 + e], s);
    city_l[tid] = s;
  }

  float4 accL[8], accH[8];
#pragma unroll
  for (int j = 0; j < 8; ++j) {
    accL[j] = make_float4(0.f, 0.f, 0.f, 0.f);
    accH[j] = make_float4(0.f, 0.f, 0.f, 0.f);
  }

  // staging coords: A tile 128 rows x 16 float4 (2048 f4 / 512 thr = 4 each),
  // W chunk 64 rows x 8 float4 (512 f4 = 1 each). All coalesced.
  const int arow = tid >> 4, acol = (tid & 15) * 4;
  const int wrow = tid >> 3, wcol = tid & 7;

  float4 AR0, AR1, AR2, AR3, WR;  // named regs: no scratch

  auto a_src = [&](int g, int row) -> const float* {
    const float* base; int stride;
    if (g < 16)      { base = mh + g * 64;        stride = 1024; }
    else if (g < 20) { base = dt + (g - 16) * 64; stride = 256; }
    else if (g < 24) { base = dd + (g - 20) * 64; stride = 256; }
    else if (g < 26) { base = rg + (g - 24) * 64; stride = 128; }
    else             { base = de + (g - 26) * 64; stride = 128; }
    return base + (size_t)(blockTok + row) * stride;
  };

  auto prefetch = [&](int g) {
    AR0 = *(const float4*)(a_src(g, arow +  0) + acol);
    AR1 = *(const float4*)(a_src(g, arow + 32) + acol);
    AR2 = *(const float4*)(a_src(g, arow + 64) + acol);
    AR3 = *(const float4*)(a_src(g, arow + 96) + acol);
    const int kb = g * 64 + ((g >= 16) ? 32 : 0);  // skip city rows 1024..1055
    const float* ws = (wcol < 4)
        ? (w_route + (kb + wrow) * 16 + wcol * 4)
        : (w_noise + (kb + wrow) * 16 + (wcol - 4) * 4);
    WR = *(const float4*)ws;
  };

  auto stage = [&](float* A, float* W) {
    *(float4*)&A[(arow +  0) * SA + acol] = AR0;
    *(float4*)&A[(arow + 32) * SA + acol] = AR1;
    *(float4*)&A[(arow + 64) * SA + acol] = AR2;
    *(float4*)&A[(arow + 96) * SA + acol] = AR3;
    *(float4*)&W[wrow * SW + wcol * 4] = WR;
  };

  prefetch(0);
  stage(sA0, sW0);
  __syncthreads();

  for (int c = 0; c < NCHUNK; ++c) {
    const float* A = (c & 1) ? sA1 : sA0;
    const float* W = (c & 1) ? sW1 : sW0;

    if (c + 1 < NCHUNK) prefetch(c + 1);  // global loads fly over compute

    const int k0 = w * 8;
#pragma unroll
    for (int q = 0; q < 2; ++q) {
      const int koff = k0 + q * 4;
      float4 a[8];
#pragma unroll
      for (int j = 0; j < 8; ++j)
        a[j] = *(const float4*)&A[(tg + 16 * j) * SA + koff];  // 2-way banks: free
#pragma unroll
      for (int kk = 0; kk < 4; ++kk) {
        float4 wv0 = *(const float4*)&W[(koff + kk) * SW + eg * 8];      // bcast
        float4 wv1 = *(const float4*)&W[(koff + kk) * SW + eg * 8 + 4];  // bcast
#pragma unroll
        for (int j = 0; j < 8; ++j) {
          const float s = get_comp(a[j], kk);
          accL[j].x = fmaf(s, wv0.x, accL[j].x);
          accL[j].y = fmaf(s, wv0.y, accL[j].y);
          accL[j].z = fmaf(s, wv0.z, accL[j].z);
          accL[j].w = fmaf(s, wv0.w, accL[j].w);
          accH[j].x = fmaf(s, wv1.x, accH[j].x);
          accH[j].y = fmaf(s, wv1.y, accH[j].y);
          accH[j].z = fmaf(s, wv1.z, accH[j].z);
          accH[j].w = fmaf(s, wv1.w, accH[j].w);
        }
      }
    }

    if (c + 1 < NCHUNK) stage((c & 1) ? sA0 : sA1, (c & 1) ? sW0 : sW1);
    __syncthreads();  // next buffer visible; all waves done with current
  }

  // ---- 8-way split-K reduction: serial RMW rounds into sS[128][36] ----
  // (sS overlays A-buffer 0; last chunk (c=27) computed from buffer 1)
  for (int r = 0; r < 8; ++r) {
    if (w == r) {
#pragma unroll
      for (int j = 0; j < 8; ++j) {
        float* p = &sS[(tg + 16 * j) * SS + eg * 8];
        if (r == 0) {
          *(float4*)(p)     = accL[j];
          *(float4*)(p + 4) = accH[j];
        } else {
          float4 x0 = *(float4*)(p), x1 = *(float4*)(p + 4);
          x0.x += accL[j].x; x0.y += accL[j].y; x0.z += accL[j].z; x0.w += accL[j].w;
          x1.x += accH[j].x; x1.y += accH[j].y; x1.z += accH[j].z; x1.w += accH[j].w;
          *(float4*)(p)     = x0;
          *(float4*)(p + 4) = x1;
        }
      }
    }
    __syncthreads();
  }

  // ---- epilogue: one lane per token ----
  if (tid < TOKS) {
    const int tokg = blockTok + tid;
    float l[32];
#pragma unroll
    for (int e4 = 0; e4 < 8; ++e4) {
      float4 s0 = *(const float4*)&sS[tid * SS + e4 * 4];
      l[e4 * 4 + 0] = s0.x + ((e4 * 4 + 0 < 32) ? 0.f : 0.f);
      l[e4 * 4 + 0] = s0.x; l[e4 * 4 + 1] = s0.y;
      l[e4 * 4 + 2] = s0.z; l[e4 * 4 + 3] = s0.w;
    }
#pragma unroll
    for (int e = 0; e < 32; ++e) l[e] += city_l[e];

    const float* ep = eps + (size_t)tokg * 16;
    float n[16];
#pragma unroll
    for (int e = 0; e < 16; ++e)
      n[e] = fmaf(ep[e], softplus_f(l[16 + e]), l[e]);

    // top-2, lowest-index tie-break (matches lax.top_k)
    float m1 = -INFINITY; int i1 = 0;
#pragma unroll
    for (int e = 0; e < 16; ++e)
      if (n[e] > m1) { m1 = n[e]; i1 = e; }
    float m2 = -INFINITY; int i2 = 0;
#pragma unroll
    for (int e = 0; e < 16; ++e)
      if (e != i1 && n[e] > m2) { m2 = n[e]; i2 = e; }

    float ex[16], Z = 0.f;
#pragma unroll
    for (int e = 0; e < 16; ++e) { ex[e] = expf(n[e] - m1); Z += ex[e]; }
    const float invZ  = 1.0f / Z;
    const float invZ2 = 1.0f / (1.0f + expf(m2 - m1));  // ex[i1]=1

    float r[16], g1[16];
#pragma unroll
    for (int e = 0; e < 16; ++e) {
      r[e]  = (e == i1 || e == i2) ? ex[e] * invZ2 : 0.0f;
      g1[e] = ex[e] * invZ;
    }

    float* ro = out + (size_t)tokg * 16;
#pragma unroll
    for (int e4 = 0; e4 < 4; ++e4)
      *(float4*)(ro + e4 * 4) = make_float4(r[e4*4], r[e4*4+1], r[e4*4+2], r[e4*4+3]);

    out[I_OFF + (size_t)tokg * 2 + 0] = (float)i1;
    out[I_OFF + (size_t)tokg * 2 + 1] = (float)i2;

    float* go = out + G_OFF + (size_t)tokg * 16;
#pragma unroll
    for (int e4 = 0; e4 < 4; ++e4)
      *(float4*)(go + e4 * 4) = make_float4(g1[e4*4], g1[e4*4+1], g1[e4*4+2], g1[e4*4+3]);
  }
}

extern "C" void kernel_launch(void* const* d_in, const int* in_sizes, int n_in,
                              void* d_out, int out_size, void* d_ws, size_t ws_size,
                              hipStream_t stream) {
  const float* mh = (const float*)d_in[0];   // [8,4096,1024]
  const float* dt = (const float*)d_in[1];   // [8,4096,256]
  const float* dd = (const float*)d_in[2];   // [8,4096,256]
  const float* rg = (const float*)d_in[3];   // [8,4096,128]
  const float* de = (const float*)d_in[4];   // [8,4096,128]
  const float* ce = (const float*)d_in[5];   // [4,32]
  const float* wr = (const float*)d_in[6];   // [1824,16]
  const float* br = (const float*)d_in[7];   // [16]
  const float* wn = (const float*)d_in[8];   // [1824,16]
  const float* bn = (const float*)d_in[9];   // [16]
  const float* ep = (const float*)d_in[10];  // [8,4096,16]
  const int*   ci = (const int*)d_in[11];    // scalar
  float* out = (float*)d_out;

  router_kernel<<<256, 512, 0, stream>>>(mh, dt, dd, rg, de, ce, wr, br, wn, bn,
                                         ep, ci, out);
}